// Round 6
// baseline (163.481 us; speedup 1.0000x reference)
//
#include <hip/hip_runtime.h>

// VectorQuantizer: N=131072 tokens, D=64, K=1024 codes.
// out (f32 concat): [0,8388608) quant, [8388608] loss, [8388609,...) idx.
//
// R16: software-pipelined min-update (two acc sets).
// R15 post-mortem: 4 structures (LDS-staged / 1-deep reg / 2x occupancy /
// 4-deep reg) ALL land at 68-70us, MfmaUtil~30 VALUBusy~34. Re-derived
// per-SIMD cost: 16x16x32 f16 MFMA = ~19.4 cyc/SIMD (m06 2075 TF / 1024
// SIMDs), so R15's 3072 MFMA/SIMD = 24.8us of pure MFMA-pipe time; VALU
// ~23us. The invariant all four shared: within a tile the min-update VALU
// DEPENDS on that tile's accs -> each wave alternates [24 MFMA -> wait ->
// ~80 VALU] and the phases never overlap (lockstep waves share the MFMA
// pipe, so cross-wave overlap never materializes either). 64 x (MFMAphase +
// VALUphase) was constant across all variants.
// R16: defer tile nt's min-update until after tile nt+1's MFMAs are issued
// (two named acc sets accA/accB, static indexing only): UPD(nt) executes on
// the VALU while MM(nt+1) occupies the matrix pipe -> within-wave overlap.
// Update order stays strictly ascending nt -> bit-identical results.
// Everything else verbatim R15: 64 tok/wave, 4-deep named prefetch b0..b3,
// no setprio, launch_bounds(256,2), atomicAdd loss fusion, 2 launches.
// Distance math bit-identical to R4-R15: fp16 split-product MFMA
// (hi*hi+hi*lo+lo*hi) in the same per-accumulator order, np8 x2/e2,
// s=fma(-2,dot,x2+e2), ascending-k strict-< first-min, butterfly epilogue,
// bitwise quant copy.

#define KC 1024
#define DD 64
#define NTOK (32 * 4096)
#define QUANT_ELEMS ((size_t)NTOK * DD)        // 8388608
#define LOSS_OFF QUANT_ELEMS
#define IDX_OFF (QUANT_ELEMS + 1)

// ws float-word offsets (layout identical to R10/R12)
#define WS_E2 0                      // 1024 f32
#define WS_BFRAG_F 2048              // 16384 f16x8 = 65536 f32 words

#define MAIN_BLOCKS (NTOK / 256)     // 512 blocks, 256 tokens each

typedef _Float16 f16x8 __attribute__((ext_vector_type(8)));
typedef float f32x4 __attribute__((ext_vector_type(4)));

__device__ __forceinline__ unsigned int sortable_bits(float f) {
  unsigned int b = __float_as_uint(f);
  return b ^ (unsigned int)(((int)b >> 31) | 0x80000000);
}

__device__ __forceinline__ float unsortable_bits(unsigned int u) {
  unsigned int fb = (u & 0x80000000u) ? (u ^ 0x80000000u) : ~u;
  return __uint_as_float(fb);
}

// np pairwise-8 sum of squares of a 64-float row (bit-identical to R10)
__device__ __forceinline__ float row_sumsq_np8(const float* p) {
  float r[8];
#pragma unroll
  for (int j = 0; j < 8; ++j) r[j] = p[j] * p[j];
#pragma unroll
  for (int i = 1; i < 8; ++i)
#pragma unroll
    for (int j = 0; j < 8; ++j) {
      float v = p[i * 8 + j];
      r[j] += v * v;
    }
  return ((r[0] + r[1]) + (r[2] + r[3])) + ((r[4] + r[5]) + (r[6] + r[7]));
}

// blocks [0,64): B-frag build; [64,68): e2 table (verbatim R10/R12)
// + block 64 tid 0 zeroes the loss accumulator for this iteration.
__global__ void vq_setup(const float* __restrict__ emb,
                         float* __restrict__ ws,
                         float* __restrict__ out) {
  const int b = blockIdx.x;
  const int tid = threadIdx.x;
  if (b < 64) {
    const int nt = b;                  // global tile 0..63 (16 codes each)
    const int f = tid >> 6;            // 0..3: plane(hi/lo) x kstep
    const int lane = tid & 63;
    const int plane = f >> 1, ks = f & 1;
    const int n = nt * 16 + (lane & 15);
    const int kb = ks * 32 + ((lane >> 4) & 3) * 8;
    const float* ep = emb + (size_t)n * DD + kb;
    f16x8 o;
#pragma unroll
    for (int j = 0; j < 8; ++j) {
      float v = ep[j];
      _Float16 h = (_Float16)v;
      o[j] = (plane == 0) ? h : (_Float16)(v - (float)h);
    }
    ((f16x8*)(ws + WS_BFRAG_F))[(nt * 4 + f) * 64 + lane] = o;
  } else {
    const int k = (b - 64) * 256 + tid;  // 0..1023
    ws[WS_E2 + k] = row_sumsq_np8(emb + (size_t)k * DD);
    if (b == 64 && tid == 0) out[LOSS_OFF] = 0.0f;
  }
}

__launch_bounds__(256, 2)
__global__ void vq_main(const float* __restrict__ x_in,
                        const float* __restrict__ emb,
                        const float* __restrict__ ws_ro,
                        float* __restrict__ out) {
  const int tid = threadIdx.x;
  const int wave = tid >> 6, lane = tid & 63;
  const int quad = lane >> 4, l16 = lane & 15;
  const int tokBase = blockIdx.x * 256 + wave * 64;  // 64 tokens per wave

  __shared__ float E2s[KC];    // 4 KB
  __shared__ float x2s[256];   // per-block token x2
  __shared__ float wsum[4];

  // Stage e2 table to LDS; x2 for this wave's 64 tokens (one row per lane,
  // bit-identical np8 -- value depends only on row data, not producer lane).
#pragma unroll
  for (int i = 0; i < 4; ++i)
    E2s[i * 256 + tid] = ws_ro[WS_E2 + i * 256 + tid];
  x2s[wave * 64 + lane] = row_sumsq_np8(x_in + (size_t)(tokBase + lane) * DD);

  // A fragments: 4 m-sets of 16 tokens; x split into fp16 hi/lo planes.
  f16x8 ah[4][2], al[4][2];
#pragma unroll
  for (int ms = 0; ms < 4; ++ms) {
    const float* xr = x_in + (size_t)(tokBase + ms * 16 + l16) * DD;
#pragma unroll
    for (int ks = 0; ks < 2; ++ks) {
      const float4* p4 = (const float4*)(xr + ks * 32 + quad * 8);
      float4 v0 = p4[0], v1 = p4[1];
      float vv[8] = {v0.x, v0.y, v0.z, v0.w, v1.x, v1.y, v1.z, v1.w};
#pragma unroll
      for (int j = 0; j < 8; ++j) {
        _Float16 h = (_Float16)vv[j];
        ah[ms][ks][j] = h;
        al[ms][ks][j] = (_Float16)(vv[j] - (float)h);
      }
    }
  }

  float best[4][4];
  int bidx[4][4];
#pragma unroll
  for (int ms = 0; ms < 4; ++ms)
#pragma unroll
    for (int r = 0; r < 4; ++r) { best[ms][r] = 3.402823466e38f; bidx[ms][r] = 0; }

  __syncthreads();  // E2s + x2s ready -- the ONLY barrier before epilogue

  // x2 for this lane's C rows: token = tokBase + ms*16 + quad*4 + r
  float x2v[4][4];
#pragma unroll
  for (int ms = 0; ms < 4; ++ms)
#pragma unroll
    for (int r = 0; r < 4; ++r)
      x2v[ms][r] = x2s[wave * 64 + ms * 16 + quad * 4 + r];

  const f16x8* bws = (const f16x8*)(ws_ro + WS_BFRAG_F);

  // MM: issue the 24 MFMAs for one tile into the given acc set (6-product
  // chain per ms, order identical to R4-R15, step-major across chains).
  auto MM = [&](const f16x8 (&bf)[4], f32x4 (&acc)[4]) {
#pragma unroll
    for (int ms = 0; ms < 4; ++ms) acc[ms] = (f32x4){0.f, 0.f, 0.f, 0.f};
#pragma unroll
    for (int ms = 0; ms < 4; ++ms)
      acc[ms] = __builtin_amdgcn_mfma_f32_16x16x32_f16(ah[ms][0], bf[0], acc[ms], 0, 0, 0);
#pragma unroll
    for (int ms = 0; ms < 4; ++ms)
      acc[ms] = __builtin_amdgcn_mfma_f32_16x16x32_f16(ah[ms][1], bf[1], acc[ms], 0, 0, 0);
#pragma unroll
    for (int ms = 0; ms < 4; ++ms)
      acc[ms] = __builtin_amdgcn_mfma_f32_16x16x32_f16(al[ms][0], bf[0], acc[ms], 0, 0, 0);
#pragma unroll
    for (int ms = 0; ms < 4; ++ms)
      acc[ms] = __builtin_amdgcn_mfma_f32_16x16x32_f16(al[ms][1], bf[1], acc[ms], 0, 0, 0);
#pragma unroll
    for (int ms = 0; ms < 4; ++ms)
      acc[ms] = __builtin_amdgcn_mfma_f32_16x16x32_f16(ah[ms][0], bf[2], acc[ms], 0, 0, 0);
#pragma unroll
    for (int ms = 0; ms < 4; ++ms)
      acc[ms] = __builtin_amdgcn_mfma_f32_16x16x32_f16(ah[ms][1], bf[3], acc[ms], 0, 0, 0);
  };

  // UPD: first-min update for tile nt from a completed acc set. Called in
  // strictly ascending nt order -> bit-identical to the fused version.
  auto UPD = [&](int nt, const f32x4 (&acc)[4]) {
    const int ncur = nt * 16 + l16;       // this lane's code column
    const float e2v = E2s[ncur];
#pragma unroll
    for (int ms = 0; ms < 4; ++ms)
#pragma unroll
      for (int r = 0; r < 4; ++r) {
        float s = __builtin_fmaf(-2.0f, acc[ms][r], x2v[ms][r] + e2v);
        if (s < best[ms][r]) { best[ms][r] = s; bidx[ms][r] = ncur; }
      }
  };

  // Barrier-free main loop: 64 code-tiles, 4-deep named prefetch, 2-stage
  // acc pipeline: UPD(nt) runs on the VALU while MM(nt+1)'s MFMAs execute.
  f16x8 b0[4], b1[4], b2[4], b3[4];
#pragma unroll
  for (int i = 0; i < 4; ++i) b0[i] = bws[(0 * 4 + i) * 64 + lane];
#pragma unroll
  for (int i = 0; i < 4; ++i) b1[i] = bws[(1 * 4 + i) * 64 + lane];
#pragma unroll
  for (int i = 0; i < 4; ++i) b2[i] = bws[(2 * 4 + i) * 64 + lane];
#pragma unroll
  for (int i = 0; i < 4; ++i) b3[i] = bws[(3 * 4 + i) * 64 + lane];

  f32x4 accA[4], accB[4];
  MM(b0, accA);  // tile 0

  for (int nt = 0; nt < 60; nt += 4) {
    MM(b1, accB);                         // tile nt+1
    UPD(nt + 0, accA);
#pragma unroll
    for (int i = 0; i < 4; ++i) b0[i] = bws[((nt + 4) * 4 + i) * 64 + lane];
    MM(b2, accA);                         // tile nt+2
    UPD(nt + 1, accB);
#pragma unroll
    for (int i = 0; i < 4; ++i) b1[i] = bws[((nt + 5) * 4 + i) * 64 + lane];
    MM(b3, accB);                         // tile nt+3
    UPD(nt + 2, accA);
#pragma unroll
    for (int i = 0; i < 4; ++i) b2[i] = bws[((nt + 6) * 4 + i) * 64 + lane];
    MM(b0, accA);                         // tile nt+4
    UPD(nt + 3, accB);
#pragma unroll
    for (int i = 0; i < 4; ++i) b3[i] = bws[((nt + 7) * 4 + i) * 64 + lane];
  }
  // After loop: accA holds tile 60; UPD done through tile 59;
  // b1,b2,b3 hold tiles 61,62,63.
  MM(b1, accB);
  UPD(60, accA);
  MM(b2, accA);
  UPD(61, accB);
  MM(b3, accB);
  UPD(62, accA);
  UPD(63, accB);

  // Butterfly min across each quad's 16 lanes -> ALL lanes hold the winner.
  unsigned long long key[4][4];
#pragma unroll
  for (int ms = 0; ms < 4; ++ms)
#pragma unroll
    for (int r = 0; r < 4; ++r) {
      unsigned long long k =
          ((unsigned long long)sortable_bits(best[ms][r]) << 32) |
          (unsigned int)bidx[ms][r];
#pragma unroll
      for (int m = 1; m < 16; m <<= 1) {
        unsigned long long o = __shfl_xor(k, m);
        k = o < k ? o : k;
      }
      key[ms][r] = k;
    }

  // Fused epilogue: idx store (quad lane 0), quant gather+store (all lanes),
  // loss partial decoded from keys.
  float qsum = 0.0f;
#pragma unroll
  for (int ms = 0; ms < 4; ++ms)
#pragma unroll
    for (int r = 0; r < 4; ++r) {
      const int token = tokBase + ms * 16 + quad * 4 + r;
      const int widx = (int)(unsigned int)key[ms][r];
      if (l16 == 0) out[IDX_OFF + (size_t)token] = (float)widx;
      // 16 lanes x float4 = the winning 256B row, bitwise copy
      const float4 v = ((const float4*)(emb + (size_t)widx * DD))[l16];
      ((float4*)(out + (size_t)token * DD))[l16] = v;
      qsum += unsortable_bits((unsigned int)(key[ms][r] >> 32));
    }

  // qsum identical across a quad's 16 lanes; sum the 4 quads, then 4 waves,
  // then atomicAdd the scaled partial into the loss cell (zeroed by setup).
  float tot = __shfl(qsum, 0) + __shfl(qsum, 16) +
              __shfl(qsum, 32) + __shfl(qsum, 48);
  if (lane == 0) wsum[wave] = tot;
  __syncthreads();
  if (tid == 0) {
    // 1.25f / 2^23 is exactly representable; one rounding per block.
    const float scale = 1.25f / (float)QUANT_ELEMS;
    atomicAdd(&out[LOSS_OFF], ((wsum[0] + wsum[1]) + (wsum[2] + wsum[3])) * scale);
  }
}

extern "C" void kernel_launch(void* const* d_in, const int* in_sizes, int n_in,
                              void* d_out, int out_size, void* d_ws, size_t ws_size,
                              hipStream_t stream) {
  const float* x = (const float*)d_in[0];
  const float* emb = (const float*)d_in[1];
  float* out = (float*)d_out;
  float* ws = (float*)d_ws;

  vq_setup<<<68, 256, 0, stream>>>(emb, ws, out);
  vq_main<<<MAIN_BLOCKS, 256, 0, stream>>>(x, emb, ws, out);
}

// Round 7
// 136.676 us; speedup vs baseline: 1.1961x; 1.1961x over previous
//
#include <hip/hip_runtime.h>

// VectorQuantizer: N=131072 tokens, D=64, K=1024 codes.
// out (f32 concat): [0,8388608) quant, [8388608] loss, [8388609,...) idx.
//
// R17: acc double-buffer on the R14 base (no spill this time).
// R16 post-mortem: live set ~210 VGPR; allocator capped at 128 and spilled
// (FETCH 18.5->62MB, WRITE 33->82MB = scratch round-trip). The acc-pipeline
// idea was never tested. R17 rebuilds it on R14's small base (VGPR 56
// measured): A 32 + bA/bB 32 + accA/accB 16 + best/bidx 16 + x2v 8 ~= 104.
// Structure: MM(t+1) issues its 12 MFMAs, THEN UPD(t) runs its min-update
// VALU -- the update of tile t executes while tile t+1 owns the MFMA pipe.
// UPD order strictly ascending t -> bit-identical tie semantics.
//
// Rejected this round (analysis): tile-order rotation and x2-fold-out.
// Reference distances collapse onto a ulp(64)~7.6e-6 grid via (x2+e2)-2d;
// ~10 tokens expected to have EXACT f32 ties at the min, resolved by
// ascending-k first-min. Visitation order and the comparison expression
// fma(-2,acc,x2v+e2v) must stay exactly as-is.
//
// Everything else verbatim R14: 32 tok/wave, grid 1024x256,
// launch_bounds(256,2), 1-deep b prefetch, atomicAdd loss fusion,
// 2 launches. Distance math bit-identical to R4-R16.

#define KC 1024
#define DD 64
#define NTOK (32 * 4096)
#define QUANT_ELEMS ((size_t)NTOK * DD)        // 8388608
#define LOSS_OFF QUANT_ELEMS
#define IDX_OFF (QUANT_ELEMS + 1)

// ws float-word offsets (layout identical to R10/R12)
#define WS_E2 0                      // 1024 f32
#define WS_BFRAG_F 2048              // 16384 f16x8 = 65536 f32 words

#define MAIN_BLOCKS (NTOK / 128)     // 1024 blocks, 128 tokens each

typedef _Float16 f16x8 __attribute__((ext_vector_type(8)));
typedef float f32x4 __attribute__((ext_vector_type(4)));

__device__ __forceinline__ unsigned int sortable_bits(float f) {
  unsigned int b = __float_as_uint(f);
  return b ^ (unsigned int)(((int)b >> 31) | 0x80000000);
}

__device__ __forceinline__ float unsortable_bits(unsigned int u) {
  unsigned int fb = (u & 0x80000000u) ? (u ^ 0x80000000u) : ~u;
  return __uint_as_float(fb);
}

// np pairwise-8 sum of squares of a 64-float row (bit-identical to R10)
__device__ __forceinline__ float row_sumsq_np8(const float* p) {
  float r[8];
#pragma unroll
  for (int j = 0; j < 8; ++j) r[j] = p[j] * p[j];
#pragma unroll
  for (int i = 1; i < 8; ++i)
#pragma unroll
    for (int j = 0; j < 8; ++j) {
      float v = p[i * 8 + j];
      r[j] += v * v;
    }
  return ((r[0] + r[1]) + (r[2] + r[3])) + ((r[4] + r[5]) + (r[6] + r[7]));
}

// blocks [0,64): B-frag build; [64,68): e2 table (verbatim R10/R12)
// + block 64 tid 0 zeroes the loss accumulator for this iteration.
__global__ void vq_setup(const float* __restrict__ emb,
                         float* __restrict__ ws,
                         float* __restrict__ out) {
  const int b = blockIdx.x;
  const int tid = threadIdx.x;
  if (b < 64) {
    const int nt = b;                  // global tile 0..63 (16 codes each)
    const int f = tid >> 6;            // 0..3: plane(hi/lo) x kstep
    const int lane = tid & 63;
    const int plane = f >> 1, ks = f & 1;
    const int n = nt * 16 + (lane & 15);
    const int kb = ks * 32 + ((lane >> 4) & 3) * 8;
    const float* ep = emb + (size_t)n * DD + kb;
    f16x8 o;
#pragma unroll
    for (int j = 0; j < 8; ++j) {
      float v = ep[j];
      _Float16 h = (_Float16)v;
      o[j] = (plane == 0) ? h : (_Float16)(v - (float)h);
    }
    ((f16x8*)(ws + WS_BFRAG_F))[(nt * 4 + f) * 64 + lane] = o;
  } else {
    const int k = (b - 64) * 256 + tid;  // 0..1023
    ws[WS_E2 + k] = row_sumsq_np8(emb + (size_t)k * DD);
    if (b == 64 && tid == 0) out[LOSS_OFF] = 0.0f;
  }
}

__launch_bounds__(256, 2)
__global__ void vq_main(const float* __restrict__ x_in,
                        const float* __restrict__ emb,
                        const float* __restrict__ ws_ro,
                        float* __restrict__ out) {
  const int tid = threadIdx.x;
  const int wave = tid >> 6, lane = tid & 63;
  const int quad = lane >> 4, l16 = lane & 15;
  const int blockTok = blockIdx.x * 128;
  const int tokBase = blockTok + wave * 32;  // 32 tokens per wave

  __shared__ float E2s[KC];    // 4 KB
  __shared__ float x2s[128];   // per-block token x2
  __shared__ float wsum[4];

  // Stage e2 table to LDS; x2: one row per thread for tid<128
  // (bit-identical np8 -- value depends only on row data, not producer).
#pragma unroll
  for (int i = 0; i < 4; ++i)
    E2s[i * 256 + tid] = ws_ro[WS_E2 + i * 256 + tid];
  if (tid < 128)
    x2s[tid] = row_sumsq_np8(x_in + (size_t)(blockTok + tid) * DD);

  // A fragments: 2 m-sets of 16 tokens; x split into fp16 hi/lo planes.
  f16x8 ah[2][2], al[2][2];
#pragma unroll
  for (int ms = 0; ms < 2; ++ms) {
    const float* xr = x_in + (size_t)(tokBase + ms * 16 + l16) * DD;
#pragma unroll
    for (int ks = 0; ks < 2; ++ks) {
      const float4* p4 = (const float4*)(xr + ks * 32 + quad * 8);
      float4 v0 = p4[0], v1 = p4[1];
      float vv[8] = {v0.x, v0.y, v0.z, v0.w, v1.x, v1.y, v1.z, v1.w};
#pragma unroll
      for (int j = 0; j < 8; ++j) {
        _Float16 h = (_Float16)vv[j];
        ah[ms][ks][j] = h;
        al[ms][ks][j] = (_Float16)(vv[j] - (float)h);
      }
    }
  }

  float best[2][4];
  int bidx[2][4];
#pragma unroll
  for (int ms = 0; ms < 2; ++ms)
#pragma unroll
    for (int r = 0; r < 4; ++r) { best[ms][r] = 3.402823466e38f; bidx[ms][r] = 0; }

  __syncthreads();  // E2s + x2s ready -- the ONLY barrier before epilogue

  // x2 for this lane's C rows: token = tokBase + ms*16 + quad*4 + r
  float x2v[2][4];
#pragma unroll
  for (int ms = 0; ms < 2; ++ms)
#pragma unroll
    for (int r = 0; r < 4; ++r)
      x2v[ms][r] = x2s[wave * 32 + ms * 16 + quad * 4 + r];

  const f16x8* bws = (const f16x8*)(ws_ro + WS_BFRAG_F);

  // MM: issue the 12 MFMAs for one tile into the given acc set (6-product
  // chain per ms, order identical to R4-R16, step-major across the 2
  // independent chains).
  auto MM = [&](const f16x8 (&bf)[4], f32x4 (&acc)[2]) {
#pragma unroll
    for (int ms = 0; ms < 2; ++ms) acc[ms] = (f32x4){0.f, 0.f, 0.f, 0.f};
#pragma unroll
    for (int ms = 0; ms < 2; ++ms)
      acc[ms] = __builtin_amdgcn_mfma_f32_16x16x32_f16(ah[ms][0], bf[0], acc[ms], 0, 0, 0);
#pragma unroll
    for (int ms = 0; ms < 2; ++ms)
      acc[ms] = __builtin_amdgcn_mfma_f32_16x16x32_f16(ah[ms][1], bf[1], acc[ms], 0, 0, 0);
#pragma unroll
    for (int ms = 0; ms < 2; ++ms)
      acc[ms] = __builtin_amdgcn_mfma_f32_16x16x32_f16(al[ms][0], bf[0], acc[ms], 0, 0, 0);
#pragma unroll
    for (int ms = 0; ms < 2; ++ms)
      acc[ms] = __builtin_amdgcn_mfma_f32_16x16x32_f16(al[ms][1], bf[1], acc[ms], 0, 0, 0);
#pragma unroll
    for (int ms = 0; ms < 2; ++ms)
      acc[ms] = __builtin_amdgcn_mfma_f32_16x16x32_f16(ah[ms][0], bf[2], acc[ms], 0, 0, 0);
#pragma unroll
    for (int ms = 0; ms < 2; ++ms)
      acc[ms] = __builtin_amdgcn_mfma_f32_16x16x32_f16(ah[ms][1], bf[3], acc[ms], 0, 0, 0);
  };

  // UPD: first-min update for tile nt from a completed acc set. Called in
  // strictly ascending nt order -> bit-identical tie semantics.
  auto UPD = [&](int nt, const f32x4 (&acc)[2]) {
    const int ncur = nt * 16 + l16;       // this lane's code column
    const float e2v = E2s[ncur];
#pragma unroll
    for (int ms = 0; ms < 2; ++ms)
#pragma unroll
      for (int r = 0; r < 4; ++r) {
        float s = __builtin_fmaf(-2.0f, acc[ms][r], x2v[ms][r] + e2v);
        if (s < best[ms][r]) { best[ms][r] = s; bidx[ms][r] = ncur; }
      }
  };

  // Barrier-free main loop: 64 code-tiles, 1-deep b prefetch, 2-stage acc
  // pipeline: UPD(t) runs on the VALU while MM(t+1)'s MFMAs execute.
  f16x8 bA[4], bB[4];
#pragma unroll
  for (int i = 0; i < 4; ++i) bA[i] = bws[(0 * 4 + i) * 64 + lane];
#pragma unroll
  for (int i = 0; i < 4; ++i) bB[i] = bws[(1 * 4 + i) * 64 + lane];

  f32x4 accA[2], accB[2];
  MM(bA, accA);                               // tile 0

  for (int nt = 0; nt <= 58; nt += 2) {
#pragma unroll
    for (int i = 0; i < 4; ++i) bA[i] = bws[((nt + 2) * 4 + i) * 64 + lane];
    MM(bB, accB);                             // tile nt+1
    UPD(nt + 0, accA);
#pragma unroll
    for (int i = 0; i < 4; ++i) bB[i] = bws[((nt + 3) * 4 + i) * 64 + lane];
    MM(bA, accA);                             // tile nt+2
    UPD(nt + 1, accB);
  }
  // After loop: MM done through tile 60 (accA), UPD through 59; bB = 61.
#pragma unroll
  for (int i = 0; i < 4; ++i) bA[i] = bws[(62 * 4 + i) * 64 + lane];
  MM(bB, accB);                               // tile 61
  UPD(60, accA);
#pragma unroll
  for (int i = 0; i < 4; ++i) bB[i] = bws[(63 * 4 + i) * 64 + lane];
  MM(bA, accA);                               // tile 62
  UPD(61, accB);
  MM(bB, accB);                               // tile 63
  UPD(62, accA);
  UPD(63, accB);

  // Butterfly min across each quad's 16 lanes -> ALL lanes hold the winner.
  unsigned long long key[2][4];
#pragma unroll
  for (int ms = 0; ms < 2; ++ms)
#pragma unroll
    for (int r = 0; r < 4; ++r) {
      unsigned long long k =
          ((unsigned long long)sortable_bits(best[ms][r]) << 32) |
          (unsigned int)bidx[ms][r];
#pragma unroll
      for (int m = 1; m < 16; m <<= 1) {
        unsigned long long o = __shfl_xor(k, m);
        k = o < k ? o : k;
      }
      key[ms][r] = k;
    }

  // Fused epilogue: idx store (quad lane 0), quant gather+store (all lanes),
  // loss partial decoded from keys.
  float qsum = 0.0f;
#pragma unroll
  for (int ms = 0; ms < 2; ++ms)
#pragma unroll
    for (int r = 0; r < 4; ++r) {
      const int token = tokBase + ms * 16 + quad * 4 + r;
      const int widx = (int)(unsigned int)key[ms][r];
      if (l16 == 0) out[IDX_OFF + (size_t)token] = (float)widx;
      // 16 lanes x float4 = the winning 256B row, bitwise copy
      const float4 v = ((const float4*)(emb + (size_t)widx * DD))[l16];
      ((float4*)(out + (size_t)token * DD))[l16] = v;
      qsum += unsortable_bits((unsigned int)(key[ms][r] >> 32));
    }

  // qsum identical across a quad's 16 lanes; sum the 4 quads, then 4 waves,
  // then atomicAdd the scaled partial into the loss cell (zeroed by setup).
  float tot = __shfl(qsum, 0) + __shfl(qsum, 16) +
              __shfl(qsum, 32) + __shfl(qsum, 48);
  if (lane == 0) wsum[wave] = tot;
  __syncthreads();
  if (tid == 0) {
    // 1.25f / 2^23 is exactly representable; one rounding per block.
    const float scale = 1.25f / (float)QUANT_ELEMS;
    atomicAdd(&out[LOSS_OFF], ((wsum[0] + wsum[1]) + (wsum[2] + wsum[3])) * scale);
  }
}

extern "C" void kernel_launch(void* const* d_in, const int* in_sizes, int n_in,
                              void* d_out, int out_size, void* d_ws, size_t ws_size,
                              hipStream_t stream) {
  const float* x = (const float*)d_in[0];
  const float* emb = (const float*)d_in[1];
  float* out = (float*)d_out;
  float* ws = (float*)d_ws;

  vq_setup<<<68, 256, 0, stream>>>(emb, ws, out);
  vq_main<<<MAIN_BLOCKS, 256, 0, stream>>>(x, emb, ws, out);
}

// Round 8
// 136.589 us; speedup vs baseline: 1.1969x; 1.0006x over previous
//
#include <hip/hip_runtime.h>

// VectorQuantizer: N=131072 tokens, D=64, K=1024 codes.
// out (f32 concat): [0,8388608) quant, [8388608] loss, [8388609,...) idx.
//
// R18: break the wave convoy with static priority asymmetry.
// R17 post-mortem: clean counters (VGPR 68, no spill), acc double-buffer in
// place -- still 69us. FIVE structures now at 68-70us. Accounting per
// tile-step per SIMD: MFMA ~930 cyc + VALU ~980 + vL1D return ~1024 ~= sum
// ~2930 ~= measured 2590. Three resources each ~35% busy, ~zero overlap:
// all resident waves run the same loop and phase-lock (convoy) -- every
// wave does MFMA at the same time, then VALU at the same time. Within-wave
// reordering (R15/R16/R17) can't fix cross-wave phase lock.
// R18: odd waves run at s_setprio(1) for the WHOLE kernel (set once after
// the barrier). Persistent asymmetric priority makes high-prio waves run
// ahead -> stable phase offset -> wave A's MFMA overlaps wave B's
// UPD/VMEM. (Distinct from the uniform setprio-around-MFMA that measured
// null in lockstep GEMM m190: this is asymmetric + persistent.)
// Pure scheduler hint: all math/order byte-identical to R17.
//
// Everything else verbatim R17 (= R14 base + acc double-buffer): 32
// tok/wave, grid 1024x256, launch_bounds(256,2), 1-deep b prefetch,
// MM(t+1)-then-UPD(t) acc pipeline, atomicAdd loss fusion, 2 launches.
// Distance math bit-identical to R4-R17: fp16 split-product MFMA
// (hi*hi+hi*lo+lo*hi) in the same per-accumulator order, np8 x2/e2,
// s=fma(-2,dot,x2v+e2v), ascending-k strict-< first-min, butterfly
// epilogue, bitwise quant copy.

#define KC 1024
#define DD 64
#define NTOK (32 * 4096)
#define QUANT_ELEMS ((size_t)NTOK * DD)        // 8388608
#define LOSS_OFF QUANT_ELEMS
#define IDX_OFF (QUANT_ELEMS + 1)

// ws float-word offsets (layout identical to R10/R12)
#define WS_E2 0                      // 1024 f32
#define WS_BFRAG_F 2048              // 16384 f16x8 = 65536 f32 words

#define MAIN_BLOCKS (NTOK / 128)     // 1024 blocks, 128 tokens each

typedef _Float16 f16x8 __attribute__((ext_vector_type(8)));
typedef float f32x4 __attribute__((ext_vector_type(4)));

__device__ __forceinline__ unsigned int sortable_bits(float f) {
  unsigned int b = __float_as_uint(f);
  return b ^ (unsigned int)(((int)b >> 31) | 0x80000000);
}

__device__ __forceinline__ float unsortable_bits(unsigned int u) {
  unsigned int fb = (u & 0x80000000u) ? (u ^ 0x80000000u) : ~u;
  return __uint_as_float(fb);
}

// np pairwise-8 sum of squares of a 64-float row (bit-identical to R10)
__device__ __forceinline__ float row_sumsq_np8(const float* p) {
  float r[8];
#pragma unroll
  for (int j = 0; j < 8; ++j) r[j] = p[j] * p[j];
#pragma unroll
  for (int i = 1; i < 8; ++i)
#pragma unroll
    for (int j = 0; j < 8; ++j) {
      float v = p[i * 8 + j];
      r[j] += v * v;
    }
  return ((r[0] + r[1]) + (r[2] + r[3])) + ((r[4] + r[5]) + (r[6] + r[7]));
}

// blocks [0,64): B-frag build; [64,68): e2 table (verbatim R10/R12)
// + block 64 tid 0 zeroes the loss accumulator for this iteration.
__global__ void vq_setup(const float* __restrict__ emb,
                         float* __restrict__ ws,
                         float* __restrict__ out) {
  const int b = blockIdx.x;
  const int tid = threadIdx.x;
  if (b < 64) {
    const int nt = b;                  // global tile 0..63 (16 codes each)
    const int f = tid >> 6;            // 0..3: plane(hi/lo) x kstep
    const int lane = tid & 63;
    const int plane = f >> 1, ks = f & 1;
    const int n = nt * 16 + (lane & 15);
    const int kb = ks * 32 + ((lane >> 4) & 3) * 8;
    const float* ep = emb + (size_t)n * DD + kb;
    f16x8 o;
#pragma unroll
    for (int j = 0; j < 8; ++j) {
      float v = ep[j];
      _Float16 h = (_Float16)v;
      o[j] = (plane == 0) ? h : (_Float16)(v - (float)h);
    }
    ((f16x8*)(ws + WS_BFRAG_F))[(nt * 4 + f) * 64 + lane] = o;
  } else {
    const int k = (b - 64) * 256 + tid;  // 0..1023
    ws[WS_E2 + k] = row_sumsq_np8(emb + (size_t)k * DD);
    if (b == 64 && tid == 0) out[LOSS_OFF] = 0.0f;
  }
}

__launch_bounds__(256, 2)
__global__ void vq_main(const float* __restrict__ x_in,
                        const float* __restrict__ emb,
                        const float* __restrict__ ws_ro,
                        float* __restrict__ out) {
  const int tid = threadIdx.x;
  const int wave = tid >> 6, lane = tid & 63;
  const int quad = lane >> 4, l16 = lane & 15;
  const int blockTok = blockIdx.x * 128;
  const int tokBase = blockTok + wave * 32;  // 32 tokens per wave

  __shared__ float E2s[KC];    // 4 KB
  __shared__ float x2s[128];   // per-block token x2
  __shared__ float wsum[4];

  // Stage e2 table to LDS; x2: one row per thread for tid<128
  // (bit-identical np8 -- value depends only on row data, not producer).
#pragma unroll
  for (int i = 0; i < 4; ++i)
    E2s[i * 256 + tid] = ws_ro[WS_E2 + i * 256 + tid];
  if (tid < 128)
    x2s[tid] = row_sumsq_np8(x_in + (size_t)(blockTok + tid) * DD);

  // A fragments: 2 m-sets of 16 tokens; x split into fp16 hi/lo planes.
  f16x8 ah[2][2], al[2][2];
#pragma unroll
  for (int ms = 0; ms < 2; ++ms) {
    const float* xr = x_in + (size_t)(tokBase + ms * 16 + l16) * DD;
#pragma unroll
    for (int ks = 0; ks < 2; ++ks) {
      const float4* p4 = (const float4*)(xr + ks * 32 + quad * 8);
      float4 v0 = p4[0], v1 = p4[1];
      float vv[8] = {v0.x, v0.y, v0.z, v0.w, v1.x, v1.y, v1.z, v1.w};
#pragma unroll
      for (int j = 0; j < 8; ++j) {
        _Float16 h = (_Float16)vv[j];
        ah[ms][ks][j] = h;
        al[ms][ks][j] = (_Float16)(vv[j] - (float)h);
      }
    }
  }

  float best[2][4];
  int bidx[2][4];
#pragma unroll
  for (int ms = 0; ms < 2; ++ms)
#pragma unroll
    for (int r = 0; r < 4; ++r) { best[ms][r] = 3.402823466e38f; bidx[ms][r] = 0; }

  __syncthreads();  // E2s + x2s ready -- the ONLY barrier before epilogue

  // Convoy breaker: odd waves run at priority 1 for the whole main loop.
  // Persistent asymmetric priority -> stable phase offset between waves ->
  // one wave's MFMA phase overlaps another's VALU/VMEM phase.
  if (wave & 1) __builtin_amdgcn_s_setprio(1);

  // x2 for this lane's C rows: token = tokBase + ms*16 + quad*4 + r
  float x2v[2][4];
#pragma unroll
  for (int ms = 0; ms < 2; ++ms)
#pragma unroll
    for (int r = 0; r < 4; ++r)
      x2v[ms][r] = x2s[wave * 32 + ms * 16 + quad * 4 + r];

  const f16x8* bws = (const f16x8*)(ws_ro + WS_BFRAG_F);

  // MM: issue the 12 MFMAs for one tile into the given acc set (6-product
  // chain per ms, order identical to R4-R17, step-major across the 2
  // independent chains).
  auto MM = [&](const f16x8 (&bf)[4], f32x4 (&acc)[2]) {
#pragma unroll
    for (int ms = 0; ms < 2; ++ms) acc[ms] = (f32x4){0.f, 0.f, 0.f, 0.f};
#pragma unroll
    for (int ms = 0; ms < 2; ++ms)
      acc[ms] = __builtin_amdgcn_mfma_f32_16x16x32_f16(ah[ms][0], bf[0], acc[ms], 0, 0, 0);
#pragma unroll
    for (int ms = 0; ms < 2; ++ms)
      acc[ms] = __builtin_amdgcn_mfma_f32_16x16x32_f16(ah[ms][1], bf[1], acc[ms], 0, 0, 0);
#pragma unroll
    for (int ms = 0; ms < 2; ++ms)
      acc[ms] = __builtin_amdgcn_mfma_f32_16x16x32_f16(al[ms][0], bf[0], acc[ms], 0, 0, 0);
#pragma unroll
    for (int ms = 0; ms < 2; ++ms)
      acc[ms] = __builtin_amdgcn_mfma_f32_16x16x32_f16(al[ms][1], bf[1], acc[ms], 0, 0, 0);
#pragma unroll
    for (int ms = 0; ms < 2; ++ms)
      acc[ms] = __builtin_amdgcn_mfma_f32_16x16x32_f16(ah[ms][0], bf[2], acc[ms], 0, 0, 0);
#pragma unroll
    for (int ms = 0; ms < 2; ++ms)
      acc[ms] = __builtin_amdgcn_mfma_f32_16x16x32_f16(ah[ms][1], bf[3], acc[ms], 0, 0, 0);
  };

  // UPD: first-min update for tile nt from a completed acc set. Called in
  // strictly ascending nt order -> bit-identical tie semantics.
  auto UPD = [&](int nt, const f32x4 (&acc)[2]) {
    const int ncur = nt * 16 + l16;       // this lane's code column
    const float e2v = E2s[ncur];
#pragma unroll
    for (int ms = 0; ms < 2; ++ms)
#pragma unroll
      for (int r = 0; r < 4; ++r) {
        float s = __builtin_fmaf(-2.0f, acc[ms][r], x2v[ms][r] + e2v);
        if (s < best[ms][r]) { best[ms][r] = s; bidx[ms][r] = ncur; }
      }
  };

  // Barrier-free main loop: 64 code-tiles, 1-deep b prefetch, 2-stage acc
  // pipeline: UPD(t) runs on the VALU while MM(t+1)'s MFMAs execute.
  f16x8 bA[4], bB[4];
#pragma unroll
  for (int i = 0; i < 4; ++i) bA[i] = bws[(0 * 4 + i) * 64 + lane];
#pragma unroll
  for (int i = 0; i < 4; ++i) bB[i] = bws[(1 * 4 + i) * 64 + lane];

  f32x4 accA[2], accB[2];
  MM(bA, accA);                               // tile 0

  for (int nt = 0; nt <= 58; nt += 2) {
#pragma unroll
    for (int i = 0; i < 4; ++i) bA[i] = bws[((nt + 2) * 4 + i) * 64 + lane];
    MM(bB, accB);                             // tile nt+1
    UPD(nt + 0, accA);
#pragma unroll
    for (int i = 0; i < 4; ++i) bB[i] = bws[((nt + 3) * 4 + i) * 64 + lane];
    MM(bA, accA);                             // tile nt+2
    UPD(nt + 1, accB);
  }
  // After loop: MM done through tile 60 (accA), UPD through 59; bB = 61.
#pragma unroll
  for (int i = 0; i < 4; ++i) bA[i] = bws[(62 * 4 + i) * 64 + lane];
  MM(bB, accB);                               // tile 61
  UPD(60, accA);
#pragma unroll
  for (int i = 0; i < 4; ++i) bB[i] = bws[(63 * 4 + i) * 64 + lane];
  MM(bA, accA);                               // tile 62
  UPD(61, accB);
  MM(bB, accB);                               // tile 63
  UPD(62, accA);
  UPD(63, accB);

  // Restore uniform priority before the shuffle/store epilogue.
  if (wave & 1) __builtin_amdgcn_s_setprio(0);

  // Butterfly min across each quad's 16 lanes -> ALL lanes hold the winner.
  unsigned long long key[2][4];
#pragma unroll
  for (int ms = 0; ms < 2; ++ms)
#pragma unroll
    for (int r = 0; r < 4; ++r) {
      unsigned long long k =
          ((unsigned long long)sortable_bits(best[ms][r]) << 32) |
          (unsigned int)bidx[ms][r];
#pragma unroll
      for (int m = 1; m < 16; m <<= 1) {
        unsigned long long o = __shfl_xor(k, m);
        k = o < k ? o : k;
      }
      key[ms][r] = k;
    }

  // Fused epilogue: idx store (quad lane 0), quant gather+store (all lanes),
  // loss partial decoded from keys.
  float qsum = 0.0f;
#pragma unroll
  for (int ms = 0; ms < 2; ++ms)
#pragma unroll
    for (int r = 0; r < 4; ++r) {
      const int token = tokBase + ms * 16 + quad * 4 + r;
      const int widx = (int)(unsigned int)key[ms][r];
      if (l16 == 0) out[IDX_OFF + (size_t)token] = (float)widx;
      // 16 lanes x float4 = the winning 256B row, bitwise copy
      const float4 v = ((const float4*)(emb + (size_t)widx * DD))[l16];
      ((float4*)(out + (size_t)token * DD))[l16] = v;
      qsum += unsortable_bits((unsigned int)(key[ms][r] >> 32));
    }

  // qsum identical across a quad's 16 lanes; sum the 4 quads, then 4 waves,
  // then atomicAdd the scaled partial into the loss cell (zeroed by setup).
  float tot = __shfl(qsum, 0) + __shfl(qsum, 16) +
              __shfl(qsum, 32) + __shfl(qsum, 48);
  if (lane == 0) wsum[wave] = tot;
  __syncthreads();
  if (tid == 0) {
    // 1.25f / 2^23 is exactly representable; one rounding per block.
    const float scale = 1.25f / (float)QUANT_ELEMS;
    atomicAdd(&out[LOSS_OFF], ((wsum[0] + wsum[1]) + (wsum[2] + wsum[3])) * scale);
  }
}

extern "C" void kernel_launch(void* const* d_in, const int* in_sizes, int n_in,
                              void* d_out, int out_size, void* d_ws, size_t ws_size,
                              hipStream_t stream) {
  const float* x = (const float*)d_in[0];
  const float* emb = (const float*)d_in[1];
  float* out = (float*)d_out;
  float* ws = (float*)d_ws;

  vq_setup<<<68, 256, 0, stream>>>(emb, ws, out);
  vq_main<<<MAIN_BLOCKS, 256, 0, stream>>>(x, emb, ws, out);
}